// Round 7
// baseline (244.681 us; speedup 1.0000x reference)
//
#include <hip/hip_runtime.h>

#define NB 1024
#define NR 100

typedef _Float16 half_t;
typedef half_t f16x8 __attribute__((ext_vector_type(8)));
typedef float f32x4 __attribute__((ext_vector_type(4)));

// fragment k-map used CONSISTENTLY for all A and B operands:
// k_local = g*4 + (j&3) + 16*(j>>2)   (g = lane>>4, j = elem 0..7)
__device__ __forceinline__ int kmap2(int g, int j) {
    return g*4 + (j & 3) + ((j >> 2) << 4);
}

// async global->LDS, 16B per lane; LDS dest = base + lane*16 (HW behavior)
#define GLDS(gsrc, ldst) \
    __builtin_amdgcn_global_load_lds( \
        (const __attribute__((address_space(1))) void*)(gsrc), \
        (__attribute__((address_space(3))) void*)(ldst), 16, 0, 0)

// ---------------------------------------------------------------------------
// conv1: x[B,1,98,98] -> out[B,6,49,49]   (conv 3x3 pad1 + relu + maxpool2)
// ---------------------------------------------------------------------------
__global__ __launch_bounds__(256) void conv1_k(const float* __restrict__ x,
        const float* __restrict__ w, const float* __restrict__ bias,
        float* __restrict__ out) {
    __shared__ float img[98*98];
    const int b = blockIdx.x;
    const int tid = threadIdx.x;
    const float* xb = x + (size_t)b * 9604;
    for (int i = tid; i < 2401; i += 256)
        ((float4*)img)[i] = ((const float4*)xb)[i];
    __syncthreads();
    for (int pos = tid; pos < 2401; pos += 256) {
        const int py = pos / 49, px = pos % 49;
        const int y0 = 2*py - 1, x0 = 2*px - 1;
        float p[4][4];
        #pragma unroll
        for (int dy = 0; dy < 4; ++dy) {
            const int iy = y0 + dy;
            #pragma unroll
            for (int dx = 0; dx < 4; ++dx) {
                const int ix = x0 + dx;
                p[dy][dx] = (iy >= 0 && iy < 98 && ix >= 0 && ix < 98)
                            ? img[iy*98 + ix] : 0.f;
            }
        }
        #pragma unroll
        for (int c = 0; c < 6; ++c) {
            const float bv = bias[c];
            float v0 = bv, v1 = bv, v2 = bv, v3 = bv;
            #pragma unroll
            for (int ky = 0; ky < 3; ++ky) {
                #pragma unroll
                for (int kx = 0; kx < 3; ++kx) {
                    const float wv = w[c*9 + ky*3 + kx];   // uniform -> s_load
                    v0 = fmaf(wv, p[ky  ][kx  ], v0);
                    v1 = fmaf(wv, p[ky  ][kx+1], v1);
                    v2 = fmaf(wv, p[ky+1][kx  ], v2);
                    v3 = fmaf(wv, p[ky+1][kx+1], v3);
                }
            }
            float m = fmaxf(fmaxf(v0, v1), fmaxf(v2, v3));
            out[((size_t)b*6 + c)*2401 + pos] = fmaxf(m, 0.f);
        }
    }
}

// ---------------------------------------------------------------------------
// conv2 v3b: in[B,6,49,49] -> out[B,4,22,22]  (conv 6x6 VALID + relu + pool)
// 2 blocks/image (11 pooled rows). Row stride 64 (power-of-2 domain so the
// XOR swizzle is bijective WITHIN the row — the stride-56 version overflowed).
// Waves 0-1: oc {0,1}; waves 2-3: oc {2,3} (wave-uniform -> scalar weights).
// ---------------------------------------------------------------------------
#define SWZ(r, c) ((c) ^ ((((r) >> 1) & 3) << 3))

__global__ __launch_bounds__(256, 4) void conv2_k(const float* __restrict__ in,
        const float* __restrict__ w, const float* __restrict__ bias,
        float* __restrict__ out) {
    __shared__ float smc[6*27*64];      // 41.5 KB
    const int blk = blockIdx.x;
    const int b  = blk >> 1;
    const int qb = blk & 1;             // row half
    const int r0 = qb * 22;             // first staged input row
    const int tid = threadIdx.x;
    const float* src = in + (size_t)b * 14406;
    for (int ic = 0; ic < 6; ++ic)
        for (int j = tid; j < 1323; j += 256) {
            const int rr = j / 49, cc = j - rr*49;
            smc[ic*1728 + rr*64 + SWZ(rr, cc)] =
                src[ic*2401 + (size_t)(r0 + rr)*49 + cc];
        }
    __syncthreads();

    const int wv_ = tid >> 6;
    const int ocg = __builtin_amdgcn_readfirstlane(tid >> 7);  // wave-uniform
    const int unit = ((wv_ & 1) << 6) | (tid & 63);            // 0..127
    if (unit >= 121) return;
    const int py = unit / 11, q = unit - py*11;   // pooled row / col-pair
    const int y0 = 2*py;                          // local conv row base
    const int x0 = 4*q;                           // local input col base

    // precompute 35 swizzled LDS byte offsets (ic=0 plane)
    int aofs[7][5];
    #pragma unroll
    for (int u = 0; u < 7; ++u) {
        const int rr = y0 + u;
        #pragma unroll
        for (int vi = 0; vi < 5; ++vi)
            aofs[u][vi] = (rr*64 + SWZ(rr, x0 + 2*vi)) * 4;
    }

    const float* wg = w + (size_t)ocg * 432;      // scalar base
    float acc[2][2][4];
    #pragma unroll
    for (int o = 0; o < 2; ++o) {
        const float bv = bias[ocg*2 + o];
        #pragma unroll
        for (int dy = 0; dy < 2; ++dy)
            #pragma unroll
            for (int dx = 0; dx < 4; ++dx) acc[o][dy][dx] = bv;
    }

    #pragma unroll
    for (int ic = 0; ic < 6; ++ic) {
        const char* plane = (const char*)smc + ic*6912;
        #pragma unroll
        for (int u = 0; u < 7; ++u) {
            float pr[9];
            #pragma unroll
            for (int vi = 0; vi < 4; ++vi)
                *(float2*)&pr[vi*2] = *(const float2*)(plane + aofs[u][vi]);
            pr[8] = *(const float*)(plane + aofs[u][4]);
            #pragma unroll
            for (int dy = 0; dy < 2; ++dy) {
                const int ky = u - dy;
                if (ky < 0 || ky > 5) continue;
                #pragma unroll
                for (int kx = 0; kx < 6; ++kx) {
                    const float w0 = wg[      ic*36 + ky*6 + kx];
                    const float w1 = wg[216 + ic*36 + ky*6 + kx];
                    #pragma unroll
                    for (int dx = 0; dx < 4; ++dx) {
                        acc[0][dy][dx] = fmaf(w0, pr[dx+kx], acc[0][dy][dx]);
                        acc[1][dy][dx] = fmaf(w1, pr[dx+kx], acc[1][dy][dx]);
                    }
                }
            }
        }
    }

    const int PY = qb*11 + py;
    #pragma unroll
    for (int o = 0; o < 2; ++o) {
        const int oc = ocg*2 + o;
        float2 ov;
        ov.x = fmaxf(fmaxf(fmaxf(acc[o][0][0], acc[o][0][1]),
                           fmaxf(acc[o][1][0], acc[o][1][1])), 0.f);
        ov.y = fmaxf(fmaxf(fmaxf(acc[o][0][2], acc[o][0][3]),
                           fmaxf(acc[o][1][2], acc[o][1][3])), 0.f);
        *(float2*)(out + (((size_t)b*4 + oc)*22 + PY)*22 + 2*q) = ov;
    }
}

// ---------------------------------------------------------------------------
// conv3: in[B,4,22,22] -> out[B,200]
// ---------------------------------------------------------------------------
__global__ __launch_bounds__(256) void conv3_k(const float* __restrict__ in,
        const float* __restrict__ w, const float* __restrict__ bias,
        float* __restrict__ out) {
    __shared__ float sm[1936];
    const int b = blockIdx.x;
    const int tid = threadIdx.x;
    const float* src = in + (size_t)b * 1936;
    for (int i = tid; i < 484; i += 256)
        ((float4*)sm)[i] = ((const float4*)src)[i];
    __syncthreads();
    if (tid < 200) {
        const int c = tid / 100;
        const int rem = tid % 100;
        const int py = rem / 10, px = rem % 10;
        const int y0 = 2*py, x0 = 2*px;
        float a0, a1, a2, a3;
        a0 = a1 = a2 = a3 = bias[c];
        #pragma unroll
        for (int ic = 0; ic < 4; ++ic) {
            float p[4][4];
            const float* base = sm + ic*484 + y0*22 + x0;
            #pragma unroll
            for (int u = 0; u < 4; ++u)
                #pragma unroll
                for (int v = 0; v < 4; ++v)
                    p[u][v] = base[u*22 + v];
            #pragma unroll
            for (int ky = 0; ky < 3; ++ky) {
                #pragma unroll
                for (int kx = 0; kx < 3; ++kx) {
                    const float wv = w[(c*4 + ic)*9 + ky*3 + kx];
                    a0 = fmaf(wv, p[ky  ][kx  ], a0);
                    a1 = fmaf(wv, p[ky  ][kx+1], a1);
                    a2 = fmaf(wv, p[ky+1][kx  ], a2);
                    a3 = fmaf(wv, p[ky+1][kx+1], a3);
                }
            }
        }
        float m = fmaxf(fmaxf(a0, a1), fmaxf(a2, a3));
        out[(size_t)b*200 + tid] = fmaxf(m, 0.f);
    }
}

// ---------------------------------------------------------------------------
// f32 GEMM (fc1 / fc2), 128x64 tile. G0OUT: write packed f16 hi/lo fragment
// planes (B-fragment layout for the head kernel) instead of f32 C.
// ---------------------------------------------------------------------------
template<bool G0OUT>
__global__ __launch_bounds__(256, 4) void gemm_k(
        const float* __restrict__ A, int lda,
        const float* __restrict__ W, const float* __restrict__ bias,
        float* __restrict__ C, int ldc,
        int M, int N, int K,
        half_t* __restrict__ g0h, half_t* __restrict__ g0l) {
    __shared__ float As[32][132];
    __shared__ float Ws[32][64];
    const int m0 = blockIdx.y * 128;
    const int n0 = blockIdx.x * 64;
    const int tid = threadIdx.x;
    const int ti = tid >> 4, tj = tid & 15;
    float acc[8][4];
    #pragma unroll
    for (int i = 0; i < 8; ++i)
        #pragma unroll
        for (int j = 0; j < 4; ++j) acc[i][j] = 0.f;

    for (int k0 = 0; k0 < K; k0 += 32) {
        #pragma unroll
        for (int i = 0; i < 4; ++i) {
            const int f = tid + i*256;
            const int m = f >> 3, kg = f & 7;
            const int kk = kg*4;
            float4 v = make_float4(0.f, 0.f, 0.f, 0.f);
            if (k0 + kk < K)
                v = *(const float4*)(A + (long)(m0 + m)*lda + k0 + kk);
            As[kk+0][m] = v.x;
            As[kk+1][m] = v.y;
            As[kk+2][m] = v.z;
            As[kk+3][m] = v.w;
        }
        #pragma unroll
        for (int i = 0; i < 2; ++i) {
            const int f = tid + i*256;
            const int kk = f >> 4, cg = f & 15;
            const int n = n0 + cg*4;
            float4 v = make_float4(0.f, 0.f, 0.f, 0.f);
            if (k0 + kk < K) {
                const float* wp = W + (long)(k0 + kk)*N;
                if (n + 3 < N) v = *(const float4*)(wp + n);
                else {
                    if (n+0 < N) v.x = wp[n+0];
                    if (n+1 < N) v.y = wp[n+1];
                    if (n+2 < N) v.z = wp[n+2];
                }
            }
            *(float4*)&Ws[kk][cg*4] = v;
        }
        __syncthreads();
        #pragma unroll
        for (int kk = 0; kk < 32; ++kk) {
            float a[8], wv[4];
            *(float4*)&a[0] = *(const float4*)&As[kk][ti*8];
            *(float4*)&a[4] = *(const float4*)&As[kk][ti*8 + 4];
            *(float4*)&wv[0] = *(const float4*)&Ws[kk][tj*4];
            #pragma unroll
            for (int i = 0; i < 8; ++i)
                #pragma unroll
                for (int j = 0; j < 4; ++j)
                    acc[i][j] = fmaf(a[i], wv[j], acc[i][j]);
        }
        __syncthreads();
    }

    const int nb = n0 + tj*4;
    float bv[4] = {0.f, 0.f, 0.f, 0.f};
    #pragma unroll
    for (int e = 0; e < 4; ++e) if (nb + e < N) bv[e] = bias[nb + e];

    if (!G0OUT) {
        #pragma unroll
        for (int i = 0; i < 8; ++i) {
            const long m = m0 + ti*8 + i;
            if (nb + 3 < N) {
                float4 v;
                v.x = fmaxf(acc[i][0] + bv[0], 0.f);
                v.y = fmaxf(acc[i][1] + bv[1], 0.f);
                v.z = fmaxf(acc[i][2] + bv[2], 0.f);
                v.w = fmaxf(acc[i][3] + bv[3], 0.f);
                *(float4*)(C + m*(long)ldc + nb) = v;
            } else {
                #pragma unroll
                for (int j = 0; j < 4; ++j)
                    if (nb + j < N)
                        C[m*(long)ldc + nb + j] = fmaxf(acc[i][j] + bv[j], 0.f);
            }
        }
    } else {
        #pragma unroll
        for (int i = 0; i < 8; ++i) {
            const int m = m0 + ti*8 + i;
            #pragma unroll
            for (int j = 0; j < 4; ++j) {
                const int k = nb + j;
                if (k < N) {
                    const float v = fmaxf(acc[i][j] + bv[j], 0.f);
                    const half_t hi = (half_t)v;
                    const half_t lo = (half_t)(v - (float)hi);
                    const int kc = k >> 5, klo = k & 31;
                    const int h = klo >> 4, rm = klo & 15;
                    const int gg = rm >> 2, rr = rm & 3;
                    const size_t idx =
                        ((size_t)((m >> 4)*7 + kc)*64 + (gg << 4) + (m & 15))*8
                        + h*4 + rr;
                    g0h[idx] = hi;
                    g0l[idx] = lo;
                }
            }
        }
    }
}

// ---------------------------------------------------------------------------
// wsplit: all 4 head weight arrays f32 -> fragment-ordered f16 hi/lo planes.
// ---------------------------------------------------------------------------
__global__ __launch_bounds__(256) void wsplit_k(
        const float* __restrict__ w1, const float* __restrict__ w2,
        const float* __restrict__ w3, const float* __restrict__ w4,
        half_t* __restrict__ f1h, half_t* __restrict__ f1l,
        half_t* __restrict__ f2h, half_t* __restrict__ f2l,
        half_t* __restrict__ f3h, half_t* __restrict__ f3l,
        half_t* __restrict__ f4h, half_t* __restrict__ f4l) {
    __shared__ float lds[32*140];
    const int cx = blockIdx.x, r = blockIdx.y, tid = threadIdx.x;
    int K, N, KC, NF, kc;
    const float* src;
    half_t *dh, *dl;
    if (cx < 7)       { K=200; N=140; KC=7; NF=9; kc=cx;    src=w1; dh=f1h; dl=f1l; }
    else if (cx < 12) { K=140; N=84;  KC=5; NF=6; kc=cx-7;  src=w2; dh=f2h; dl=f2l; }
    else if (cx < 15) { K=84;  N=42;  KC=3; NF=3; kc=cx-12; src=w3; dh=f3h; dl=f3l; }
    else              { K=42;  N=4;   KC=2; NF=1; kc=cx-15; src=w4; dh=f4h; dl=f4l; }
    const float* sb = src + (size_t)r * K * N;
    for (int i = tid; i < 32*N; i += 256) {
        const int kk = i / N, n = i - kk*N;
        const int kg = kc*32 + kk;
        lds[kk*N + n] = (kg < K) ? sb[(size_t)kg*N + n] : 0.f;
    }
    __syncthreads();
    const size_t base = ((size_t)r*KC + kc)*NF*512;
    for (int e = tid; e < NF*512; e += 256) {
        const int nf = e >> 9, rem = e & 511;
        const int l = rem >> 3, j = rem & 7;
        const int g = l >> 4, c = l & 15;
        const int kl = kmap2(g, j);
        const int n = nf*16 + c;
        const float v = (n < N) ? lds[kl*N + n] : 0.f;
        const half_t hi = (half_t)v;
        const half_t lo = (half_t)(v - (float)hi);
        dh[base + (size_t)nf*512 + rem] = hi;
        dl[base + (size_t)nf*512 + rem] = lo;
    }
}

// ---------------------------------------------------------------------------
// head_k: per-radical chain 200->140->84->42->4 fused, split-f16 MFMA.
// Weights LDS-staged per block; XCD-swizzled grid for L2 locality.
// ---------------------------------------------------------------------------
#define MFMA(a, b, c) __builtin_amdgcn_mfma_f32_16x16x32_f16(a, b, c, 0, 0, 0)

__global__ __launch_bounds__(256, 4) void head_k(
        const half_t* __restrict__ g0h, const half_t* __restrict__ g0l,
        const half_t* __restrict__ w1h, const half_t* __restrict__ w1l,
        const half_t* __restrict__ w2h, const half_t* __restrict__ w2l,
        const half_t* __restrict__ w3h, const half_t* __restrict__ w3l,
        const half_t* __restrict__ w4h, const half_t* __restrict__ w4l,
        const float* __restrict__ b1, const float* __restrict__ b2,
        const float* __restrict__ b3, const float* __restrict__ b4,
        float* __restrict__ out) {
    __shared__ half_t wb[18*512];
    __shared__ float bl[270];
    const int bid = blockIdx.x;
    const int cx  = bid & 7;
    const int kb  = bid >> 3;
    const int r   = ((kb >> 3) << 3) + cx;
    if (r >= NR) return;
    const int mt  = kb & 7;
    const int tid = threadIdx.x;
    if (tid < 140) bl[tid]       = b1[(size_t)r*140 + tid];
    if (tid < 84)  bl[140 + tid] = b2[(size_t)r*84  + tid];
    if (tid < 42)  bl[224 + tid] = b3[(size_t)r*42  + tid];
    if (tid < 4)   bl[266 + tid] = b4[(size_t)r*4   + tid];
    const int w = tid >> 6, l = tid & 63;
    const int g4 = ((l >> 4) & 3) * 4;
    const int mb0 = mt*8 + w*2;
    const size_t loff = (size_t)l * 8;

    // ===================== L1: K=200 (7 chunks), N=140 (9 frags) ==========
    f32x4 a1[2][9] = {};
    for (int kc = 0; kc < 7; ++kc) {
        const half_t* hs = w1h + ((size_t)r*7 + kc)*9*512;
        const half_t* ls = w1l + ((size_t)r*7 + kc)*9*512;
        #pragma unroll
        for (int p0 = 0; p0 < 3; ++p0) {
            const int p = w + p0*4;
            if (p < 9) {
                GLDS(hs + (size_t)p*512 + loff, wb + p*512);
                GLDS(ls + (size_t)p*512 + loff, wb + (9+p)*512);
            }
        }
        f16x8 bh[2], blo[2];
        #pragma unroll
        for (int mb = 0; mb < 2; ++mb) {
            const size_t bo = ((size_t)(mb0 + mb)*7 + kc)*512 + loff;
            bh[mb]  = *(const f16x8*)(g0h + bo);
            blo[mb] = *(const f16x8*)(g0l + bo);
        }
        __syncthreads();
        #pragma unroll
        for (int nf = 0; nf < 9; ++nf) {
            const f16x8 wh = *(const f16x8*)(wb + nf*512 + loff);
            const f16x8 wl = *(const f16x8*)(wb + (9+nf)*512 + loff);
            #pragma unroll
            for (int mb = 0; mb < 2; ++mb) {
                a1[mb][nf] = MFMA(wh, bh[mb],  a1[mb][nf]);
                a1[mb][nf] = MFMA(wh, blo[mb], a1[mb][nf]);
                a1[mb][nf] = MFMA(wl, bh[mb],  a1[mb][nf]);
            }
        }
        __syncthreads();
    }
    // ---- convert a1 -> L2 B-fragments (bias+relu+split), N1=140 ----
    f16x8 b2h[2][5], b2l[2][5];
    #pragma unroll
    for (int kc = 0; kc < 5; ++kc)
        #pragma unroll
        for (int h = 0; h < 2; ++h) {
            const int nf = kc*2 + h;
            #pragma unroll
            for (int mb = 0; mb < 2; ++mb)
                #pragma unroll
                for (int rr = 0; rr < 4; ++rr) {
                    float v = 0.f;
                    if (nf < 9) {
                        const int n = nf*16 + g4 + rr;
                        v = (n < 140) ? fmaxf(a1[mb][nf][rr] + bl[n], 0.f) : 0.f;
                    }
                    const half_t hi = (half_t)v;
                    const half_t lo = (half_t)(v - (float)hi);
                    b2h[mb][kc][h*4+rr] = hi;
                    b2l[mb][kc][h*4+rr] = lo;
                }
        }
    // ===================== L2: K=140 (5 chunks), N=84 (6 frags) ===========
    f32x4 a2[2][6] = {};
    for (int kc = 0; kc < 5; ++kc) {
        const half_t* hs = w2h + ((size_t)r*5 + kc)*6*512;
        const half_t* ls = w2l + ((size_t)r*5 + kc)*6*512;
        #pragma unroll
        for (int p0 = 0; p0 < 2; ++p0) {
            const int p = w + p0*4;
            if (p < 6) {
                GLDS(hs + (size_t)p*512 + loff, wb + p*512);
                GLDS(ls + (size_t)p*512 + loff, wb + (6+p)*512);
            }
        }
        __syncthreads();
        #pragma unroll
        for (int nf = 0; nf < 6; ++nf) {
            const f16x8 wh = *(const f16x8*)(wb + nf*512 + loff);
            const f16x8 wl = *(const f16x8*)(wb + (6+nf)*512 + loff);
            #pragma unroll
            for (int mb = 0; mb < 2; ++mb) {
                a2[mb][nf] = MFMA(wh, b2h[mb][kc], a2[mb][nf]);
                a2[mb][nf] = MFMA(wh, b2l[mb][kc], a2[mb][nf]);
                a2[mb][nf] = MFMA(wl, b2h[mb][kc], a2[mb][nf]);
            }
        }
        __syncthreads();
    }
    // ---- convert a2 -> L3 B-fragments, N2=84 ----
    f16x8 b3h[2][3], b3l[2][3];
    #pragma unroll
    for (int kc = 0; kc < 3; ++kc)
        #pragma unroll
        for (int h = 0; h < 2; ++h) {
            const int nf = kc*2 + h;
            #pragma unroll
            for (int mb = 0; mb < 2; ++mb)
                #pragma unroll
                for (int rr = 0; rr < 4; ++rr) {
                    float v = 0.f;
                    if (nf < 6) {
                        const int n = nf*16 + g4 + rr;
                        v = (n < 84) ? fmaxf(a2[mb][nf][rr] + bl[140 + n], 0.f) : 0.f;
                    }
                    const half_t hi = (half_t)v;
                    const half_t lo = (half_t)(v - (float)hi);
                    b3h[mb][kc][h*4+rr] = hi;
                    b3l[mb][kc][h*4+rr] = lo;
                }
        }
    // ===================== L3: K=84 (3 chunks), N=42 (3 frags) ============
    f32x4 a3[2][3] = {};
    for (int kc = 0; kc < 3; ++kc) {
        const half_t* hs = w3h + ((size_t)r*3 + kc)*3*512;
        const half_t* ls = w3l + ((size_t)r*3 + kc)*3*512;
        {
            const int p = w;
            if (p < 3) {
                GLDS(hs + (size_t)p*512 + loff, wb + p*512);
                GLDS(ls + (size_t)p*512 + loff, wb + (3+p)*512);
            }
        }
        __syncthreads();
        #pragma unroll
        for (int nf = 0; nf < 3; ++nf) {
            const f16x8 wh = *(const f16x8*)(wb + nf*512 + loff);
            const f16x8 wl = *(const f16x8*)(wb + (3+nf)*512 + loff);
            #pragma unroll
            for (int mb = 0; mb < 2; ++mb) {
                a3[mb][nf] = MFMA(wh, b3h[mb][kc], a3[mb][nf]);
                a3[mb][nf] = MFMA(wh, b3l[mb][kc], a3[mb][nf]);
                a3[mb][nf] = MFMA(wl, b3h[mb][kc], a3[mb][nf]);
            }
        }
        __syncthreads();
    }
    // ---- convert a3 -> L4 B-fragments, N3=42 ----
    f16x8 b4h[2][2], b4l[2][2];
    #pragma unroll
    for (int kc = 0; kc < 2; ++kc)
        #pragma unroll
        for (int h = 0; h < 2; ++h) {
            const int nf = kc*2 + h;
            #pragma unroll
            for (int mb = 0; mb < 2; ++mb)
                #pragma unroll
                for (int rr = 0; rr < 4; ++rr) {
                    float v = 0.f;
                    if (nf < 3) {
                        const int n = nf*16 + g4 + rr;
                        v = (n < 42) ? fmaxf(a3[mb][nf][rr] + bl[224 + n], 0.f) : 0.f;
                    }
                    const half_t hi = (half_t)v;
                    const half_t lo = (half_t)(v - (float)hi);
                    b4h[mb][kc][h*4+rr] = hi;
                    b4l[mb][kc][h*4+rr] = lo;
                }
        }
    // ===================== L4: K=42 (2 chunks), N=4 — direct global =======
    f32x4 a4[2] = {};
    #pragma unroll
    for (int kc = 0; kc < 2; ++kc) {
        const size_t wo = ((size_t)r*2 + kc)*512 + loff;
        const f16x8 wh = *(const f16x8*)(w4h + wo);
        const f16x8 wl = *(const f16x8*)(w4l + wo);
        #pragma unroll
        for (int mb = 0; mb < 2; ++mb) {
            a4[mb] = MFMA(wh, b4h[mb][kc], a4[mb]);
            a4[mb] = MFMA(wh, b4l[mb][kc], a4[mb]);
            a4[mb] = MFMA(wl, b4h[mb][kc], a4[mb]);
        }
    }
    if ((l >> 4) == 0) {
        #pragma unroll
        for (int mb = 0; mb < 2; ++mb) {
            const int b = (mb0 + mb)*16 + (l & 15);
            float4 o;
            o.x = a4[mb][0] + bl[266];
            o.y = a4[mb][1] + bl[267];
            o.z = a4[mb][2] + bl[268];
            o.w = a4[mb][3] + bl[269];
            *(float4*)(out + (size_t)b*400 + r*4) = o;
        }
    }
}

extern "C" void kernel_launch(void* const* d_in, const int* in_sizes, int n_in,
                              void* d_out, int out_size, void* d_ws, size_t ws_size,
                              hipStream_t stream) {
    const float* x    = (const float*)d_in[0];
    const float* c1w  = (const float*)d_in[1];
    const float* c1b  = (const float*)d_in[2];
    const float* c2w  = (const float*)d_in[3];
    const float* c2b  = (const float*)d_in[4];
    const float* c3w  = (const float*)d_in[5];
    const float* c3b  = (const float*)d_in[6];
    const float* fc1w = (const float*)d_in[7];
    const float* fc1b = (const float*)d_in[8];
    const float* fc2w = (const float*)d_in[9];
    const float* fc2b = (const float*)d_in[10];
    const float* h1w  = (const float*)d_in[11];
    const float* h1b  = (const float*)d_in[12];
    const float* h2w  = (const float*)d_in[13];
    const float* h2b  = (const float*)d_in[14];
    const float* h3w  = (const float*)d_in[15];
    const float* h3b  = (const float*)d_in[16];
    const float* h4w  = (const float*)d_in[17];
    const float* h4b  = (const float*)d_in[18];
    float* out = (float*)d_out;

    char* ws = (char*)d_ws;
    size_t o = 0;
    float* t1 = (float*)(ws + o); o += (size_t)NB*6*2401*4;
    float* t2 = (float*)(ws + o); o += (size_t)NB*4*484*4;
    float* t3 = (float*)(ws + o); o += (size_t)NB*200*4;
    float* f1 = (float*)(ws + o); o += (size_t)NB*400*4;
    half_t* g0h = (half_t*)(ws + o); o += (size_t)64*7*512*2;
    half_t* g0l = (half_t*)(ws + o); o += (size_t)64*7*512*2;
    half_t* w1h = (half_t*)(ws + o); o += (size_t)NR*7*9*512*2;
    half_t* w1l = (half_t*)(ws + o); o += (size_t)NR*7*9*512*2;
    half_t* w2h = (half_t*)(ws + o); o += (size_t)NR*5*6*512*2;
    half_t* w2l = (half_t*)(ws + o); o += (size_t)NR*5*6*512*2;
    half_t* w3h = (half_t*)(ws + o); o += (size_t)NR*3*3*512*2;
    half_t* w3l = (half_t*)(ws + o); o += (size_t)NR*3*3*512*2;
    half_t* w4h = (half_t*)(ws + o); o += (size_t)NR*2*1*512*2;
    half_t* w4l = (half_t*)(ws + o); o += (size_t)NR*2*1*512*2;

    hipMemsetAsync(g0h, 0, (size_t)64*7*512*2*2, stream);

    wsplit_k<<<dim3(17, NR), 256, 0, stream>>>(h1w, h2w, h3w, h4w,
        w1h, w1l, w2h, w2l, w3h, w3l, w4h, w4l);

    conv1_k<<<NB, 256, 0, stream>>>(x, c1w, c1b, t1);
    conv2_k<<<NB*2, 256, 0, stream>>>(t1, c2w, c2b, t2);
    conv3_k<<<NB, 256, 0, stream>>>(t2, c3w, c3b, t3);

    gemm_k<false><<<dim3(7, 8), 256, 0, stream>>>(
        t3, 200, fc1w, fc1b, f1, 400, NB, 400, 200, nullptr, nullptr);
    gemm_k<true><<<dim3(4, 8), 256, 0, stream>>>(
        f1, 400, fc2w, fc2b, nullptr, 0, NB, 200, 400, g0h, g0l);

    head_k<<<832, 256, 0, stream>>>(
        g0h, g0l, w1h, w1l, w2h, w2l, w3h, w3l, w4h, w4l,
        h1b, h2b, h3b, h4b, out);

    (void)in_sizes; (void)n_in; (void)out_size; (void)ws_size;
}

// Round 8
// 229.780 us; speedup vs baseline: 1.0649x; 1.0649x over previous
//
#include <hip/hip_runtime.h>

#define NB 1024
#define NR 100

typedef _Float16 half_t;
typedef half_t f16x8 __attribute__((ext_vector_type(8)));
typedef float f32x4 __attribute__((ext_vector_type(4)));

// fragment k-map used CONSISTENTLY for all A and B operands:
// k_local = g*4 + (j&3) + 16*(j>>2)   (g = lane>>4, j = elem 0..7)
__device__ __forceinline__ int kmap2(int g, int j) {
    return g*4 + (j & 3) + ((j >> 2) << 4);
}

// async global->LDS, 16B per lane; LDS dest = base + lane*16 (HW behavior)
#define GLDS(gsrc, ldst) \
    __builtin_amdgcn_global_load_lds( \
        (const __attribute__((address_space(1))) void*)(gsrc), \
        (__attribute__((address_space(3))) void*)(ldst), 16, 0, 0)

// ---------------------------------------------------------------------------
// conv1: x[B,1,98,98] -> out[B,6,49,49]   (conv 3x3 pad1 + relu + maxpool2)
// ---------------------------------------------------------------------------
__global__ __launch_bounds__(256) void conv1_k(const float* __restrict__ x,
        const float* __restrict__ w, const float* __restrict__ bias,
        float* __restrict__ out) {
    __shared__ float img[98*98];
    const int b = blockIdx.x;
    const int tid = threadIdx.x;
    const float* xb = x + (size_t)b * 9604;
    for (int i = tid; i < 2401; i += 256)
        ((float4*)img)[i] = ((const float4*)xb)[i];
    __syncthreads();
    for (int pos = tid; pos < 2401; pos += 256) {
        const int py = pos / 49, px = pos % 49;
        const int y0 = 2*py - 1, x0 = 2*px - 1;
        float p[4][4];
        #pragma unroll
        for (int dy = 0; dy < 4; ++dy) {
            const int iy = y0 + dy;
            #pragma unroll
            for (int dx = 0; dx < 4; ++dx) {
                const int ix = x0 + dx;
                p[dy][dx] = (iy >= 0 && iy < 98 && ix >= 0 && ix < 98)
                            ? img[iy*98 + ix] : 0.f;
            }
        }
        #pragma unroll
        for (int c = 0; c < 6; ++c) {
            const float bv = bias[c];
            float v0 = bv, v1 = bv, v2 = bv, v3 = bv;
            #pragma unroll
            for (int ky = 0; ky < 3; ++ky) {
                #pragma unroll
                for (int kx = 0; kx < 3; ++kx) {
                    const float wv = w[c*9 + ky*3 + kx];   // uniform -> s_load
                    v0 = fmaf(wv, p[ky  ][kx  ], v0);
                    v1 = fmaf(wv, p[ky  ][kx+1], v1);
                    v2 = fmaf(wv, p[ky+1][kx  ], v2);
                    v3 = fmaf(wv, p[ky+1][kx+1], v3);
                }
            }
            float m = fmaxf(fmaxf(v0, v1), fmaxf(v2, v3));
            out[((size_t)b*6 + c)*2401 + pos] = fmaxf(m, 0.f);
        }
    }
}

// ---------------------------------------------------------------------------
// conv2 v4: in[B,6,49,49] -> out[B,4,22,22]  (conv 6x6 VALID + relu + pool)
// 4 blocks/image (2x2 quadrants). Row stride 32 floats (power-of-2 domain:
// swizzle bijective, c<=26 can't overflow; rows alias bank 0 so the rr>>1
// mask supplies the rotation; residual py/py+4 alias = 2-way = free).
// Waves 0-1: oc {0,1}; waves 2-3: oc {2,3} -> weights via scalar loads.
// One pooled cell per lane (121 of 128 units), row-streamed 7-wide patch.
// ---------------------------------------------------------------------------
#define SWZ2(r, c) ((c) ^ ((((r) >> 1) & 3) << 3))

__global__ __launch_bounds__(256, 4) void conv2_k(const float* __restrict__ in,
        const float* __restrict__ w, const float* __restrict__ bias,
        float* __restrict__ out) {
    __shared__ float smc[6*27*32];      // 20.25 KB
    const int blk = blockIdx.x;
    const int b  = blk >> 2;
    const int qy = (blk >> 1) & 1, qx = blk & 1;
    const int r0 = qy*22, c0 = qx*22;
    const int tid = threadIdx.x;
    const float* src = in + (size_t)b * 14406;
    {
        const int ty = tid >> 5, tx = tid & 31;   // 8 rows x 32 cols
        if (tx < 27) {
            #pragma unroll
            for (int ic = 0; ic < 6; ++ic)
                for (int rr = ty; rr < 27; rr += 8)
                    smc[ic*864 + rr*32 + SWZ2(rr, tx)] =
                        src[ic*2401 + (size_t)(r0 + rr)*49 + c0 + tx];
        }
    }
    __syncthreads();

    const int wv_ = tid >> 6;
    const int ocg = __builtin_amdgcn_readfirstlane(tid >> 7);  // wave-uniform
    const int unit = ((wv_ & 1) << 6) | (tid & 63);            // 0..127
    if (unit >= 121) return;
    const int py = unit / 11, px = unit - py*11;  // pooled cell in quadrant
    const int y0 = 2*py, x0 = 2*px;

    // precompute 28 swizzled LDS byte offsets (ic=0 plane)
    int aofs[7][4];
    #pragma unroll
    for (int u = 0; u < 7; ++u) {
        const int rr = y0 + u;
        #pragma unroll
        for (int vi = 0; vi < 3; ++vi)
            aofs[u][vi] = (rr*32 + SWZ2(rr, x0 + 2*vi)) * 4;
        aofs[u][3] = (rr*32 + SWZ2(rr, x0 + 6)) * 4;
    }

    const float* wg = w + (size_t)ocg * 432;      // scalar base
    float acc[2][2][2];                           // [oc][dy][dx]
    #pragma unroll
    for (int o = 0; o < 2; ++o) {
        const float bv = bias[ocg*2 + o];
        acc[o][0][0] = acc[o][0][1] = acc[o][1][0] = acc[o][1][1] = bv;
    }

    #pragma unroll
    for (int ic = 0; ic < 6; ++ic) {
        const char* plane = (const char*)smc + ic*3456;
        #pragma unroll
        for (int u = 0; u < 7; ++u) {
            float pr[7];
            *(float2*)&pr[0] = *(const float2*)(plane + aofs[u][0]);
            *(float2*)&pr[2] = *(const float2*)(plane + aofs[u][1]);
            *(float2*)&pr[4] = *(const float2*)(plane + aofs[u][2]);
            pr[6] = *(const float*)(plane + aofs[u][3]);
            #pragma unroll
            for (int dy = 0; dy < 2; ++dy) {
                const int ky = u - dy;
                if (ky < 0 || ky > 5) continue;
                #pragma unroll
                for (int kx = 0; kx < 6; ++kx) {
                    const float w0 = wg[      ic*36 + ky*6 + kx];
                    const float w1 = wg[216 + ic*36 + ky*6 + kx];
                    #pragma unroll
                    for (int dx = 0; dx < 2; ++dx) {
                        acc[0][dy][dx] = fmaf(w0, pr[dx+kx], acc[0][dy][dx]);
                        acc[1][dy][dx] = fmaf(w1, pr[dx+kx], acc[1][dy][dx]);
                    }
                }
            }
        }
    }

    const int PY = qy*11 + py, PX = qx*11 + px;
    #pragma unroll
    for (int o = 0; o < 2; ++o) {
        const int oc = ocg*2 + o;
        float m = fmaxf(fmaxf(acc[o][0][0], acc[o][0][1]),
                        fmaxf(acc[o][1][0], acc[o][1][1]));
        out[(((size_t)b*4 + oc)*22 + PY)*22 + PX] = fmaxf(m, 0.f);
    }
}

// ---------------------------------------------------------------------------
// conv3: in[B,4,22,22] -> out[B,200]
// ---------------------------------------------------------------------------
__global__ __launch_bounds__(256) void conv3_k(const float* __restrict__ in,
        const float* __restrict__ w, const float* __restrict__ bias,
        float* __restrict__ out) {
    __shared__ float sm[1936];
    const int b = blockIdx.x;
    const int tid = threadIdx.x;
    const float* src = in + (size_t)b * 1936;
    for (int i = tid; i < 484; i += 256)
        ((float4*)sm)[i] = ((const float4*)src)[i];
    __syncthreads();
    if (tid < 200) {
        const int c = tid / 100;
        const int rem = tid % 100;
        const int py = rem / 10, px = rem % 10;
        const int y0 = 2*py, x0 = 2*px;
        float a0, a1, a2, a3;
        a0 = a1 = a2 = a3 = bias[c];
        #pragma unroll
        for (int ic = 0; ic < 4; ++ic) {
            float p[4][4];
            const float* base = sm + ic*484 + y0*22 + x0;
            #pragma unroll
            for (int u = 0; u < 4; ++u)
                #pragma unroll
                for (int v = 0; v < 4; ++v)
                    p[u][v] = base[u*22 + v];
            #pragma unroll
            for (int ky = 0; ky < 3; ++ky) {
                #pragma unroll
                for (int kx = 0; kx < 3; ++kx) {
                    const float wv = w[(c*4 + ic)*9 + ky*3 + kx];
                    a0 = fmaf(wv, p[ky  ][kx  ], a0);
                    a1 = fmaf(wv, p[ky  ][kx+1], a1);
                    a2 = fmaf(wv, p[ky+1][kx  ], a2);
                    a3 = fmaf(wv, p[ky+1][kx+1], a3);
                }
            }
        }
        float m = fmaxf(fmaxf(a0, a1), fmaxf(a2, a3));
        out[(size_t)b*200 + tid] = fmaxf(m, 0.f);
    }
}

// ---------------------------------------------------------------------------
// f32 GEMM (fc1 / fc2), 128x64 tile. G0OUT: write packed f16 hi/lo fragment
// planes (B-fragment layout for the head kernel) instead of f32 C.
// ---------------------------------------------------------------------------
template<bool G0OUT>
__global__ __launch_bounds__(256, 4) void gemm_k(
        const float* __restrict__ A, int lda,
        const float* __restrict__ W, const float* __restrict__ bias,
        float* __restrict__ C, int ldc,
        int M, int N, int K,
        half_t* __restrict__ g0h, half_t* __restrict__ g0l) {
    __shared__ float As[32][132];
    __shared__ float Ws[32][64];
    const int m0 = blockIdx.y * 128;
    const int n0 = blockIdx.x * 64;
    const int tid = threadIdx.x;
    const int ti = tid >> 4, tj = tid & 15;
    float acc[8][4];
    #pragma unroll
    for (int i = 0; i < 8; ++i)
        #pragma unroll
        for (int j = 0; j < 4; ++j) acc[i][j] = 0.f;

    for (int k0 = 0; k0 < K; k0 += 32) {
        #pragma unroll
        for (int i = 0; i < 4; ++i) {
            const int f = tid + i*256;
            const int m = f >> 3, kg = f & 7;
            const int kk = kg*4;
            float4 v = make_float4(0.f, 0.f, 0.f, 0.f);
            if (k0 + kk < K)
                v = *(const float4*)(A + (long)(m0 + m)*lda + k0 + kk);
            As[kk+0][m] = v.x;
            As[kk+1][m] = v.y;
            As[kk+2][m] = v.z;
            As[kk+3][m] = v.w;
        }
        #pragma unroll
        for (int i = 0; i < 2; ++i) {
            const int f = tid + i*256;
            const int kk = f >> 4, cg = f & 15;
            const int n = n0 + cg*4;
            float4 v = make_float4(0.f, 0.f, 0.f, 0.f);
            if (k0 + kk < K) {
                const float* wp = W + (long)(k0 + kk)*N;
                if (n + 3 < N) v = *(const float4*)(wp + n);
                else {
                    if (n+0 < N) v.x = wp[n+0];
                    if (n+1 < N) v.y = wp[n+1];
                    if (n+2 < N) v.z = wp[n+2];
                }
            }
            *(float4*)&Ws[kk][cg*4] = v;
        }
        __syncthreads();
        #pragma unroll
        for (int kk = 0; kk < 32; ++kk) {
            float a[8], wv[4];
            *(float4*)&a[0] = *(const float4*)&As[kk][ti*8];
            *(float4*)&a[4] = *(const float4*)&As[kk][ti*8 + 4];
            *(float4*)&wv[0] = *(const float4*)&Ws[kk][tj*4];
            #pragma unroll
            for (int i = 0; i < 8; ++i)
                #pragma unroll
                for (int j = 0; j < 4; ++j)
                    acc[i][j] = fmaf(a[i], wv[j], acc[i][j]);
        }
        __syncthreads();
    }

    const int nb = n0 + tj*4;
    float bv[4] = {0.f, 0.f, 0.f, 0.f};
    #pragma unroll
    for (int e = 0; e < 4; ++e) if (nb + e < N) bv[e] = bias[nb + e];

    if (!G0OUT) {
        #pragma unroll
        for (int i = 0; i < 8; ++i) {
            const long m = m0 + ti*8 + i;
            if (nb + 3 < N) {
                float4 v;
                v.x = fmaxf(acc[i][0] + bv[0], 0.f);
                v.y = fmaxf(acc[i][1] + bv[1], 0.f);
                v.z = fmaxf(acc[i][2] + bv[2], 0.f);
                v.w = fmaxf(acc[i][3] + bv[3], 0.f);
                *(float4*)(C + m*(long)ldc + nb) = v;
            } else {
                #pragma unroll
                for (int j = 0; j < 4; ++j)
                    if (nb + j < N)
                        C[m*(long)ldc + nb + j] = fmaxf(acc[i][j] + bv[j], 0.f);
            }
        }
    } else {
        #pragma unroll
        for (int i = 0; i < 8; ++i) {
            const int m = m0 + ti*8 + i;
            #pragma unroll
            for (int j = 0; j < 4; ++j) {
                const int k = nb + j;
                if (k < N) {
                    const float v = fmaxf(acc[i][j] + bv[j], 0.f);
                    const half_t hi = (half_t)v;
                    const half_t lo = (half_t)(v - (float)hi);
                    const int kc = k >> 5, klo = k & 31;
                    const int h = klo >> 4, rm = klo & 15;
                    const int gg = rm >> 2, rr = rm & 3;
                    const size_t idx =
                        ((size_t)((m >> 4)*7 + kc)*64 + (gg << 4) + (m & 15))*8
                        + h*4 + rr;
                    g0h[idx] = hi;
                    g0l[idx] = lo;
                }
            }
        }
    }
}

// ---------------------------------------------------------------------------
// wsplit: all 4 head weight arrays f32 -> fragment-ordered f16 hi/lo planes.
// ---------------------------------------------------------------------------
__global__ __launch_bounds__(256) void wsplit_k(
        const float* __restrict__ w1, const float* __restrict__ w2,
        const float* __restrict__ w3, const float* __restrict__ w4,
        half_t* __restrict__ f1h, half_t* __restrict__ f1l,
        half_t* __restrict__ f2h, half_t* __restrict__ f2l,
        half_t* __restrict__ f3h, half_t* __restrict__ f3l,
        half_t* __restrict__ f4h, half_t* __restrict__ f4l) {
    __shared__ float lds[32*140];
    const int cx = blockIdx.x, r = blockIdx.y, tid = threadIdx.x;
    int K, N, KC, NF, kc;
    const float* src;
    half_t *dh, *dl;
    if (cx < 7)       { K=200; N=140; KC=7; NF=9; kc=cx;    src=w1; dh=f1h; dl=f1l; }
    else if (cx < 12) { K=140; N=84;  KC=5; NF=6; kc=cx-7;  src=w2; dh=f2h; dl=f2l; }
    else if (cx < 15) { K=84;  N=42;  KC=3; NF=3; kc=cx-12; src=w3; dh=f3h; dl=f3l; }
    else              { K=42;  N=4;   KC=2; NF=1; kc=cx-15; src=w4; dh=f4h; dl=f4l; }
    const float* sb = src + (size_t)r * K * N;
    for (int i = tid; i < 32*N; i += 256) {
        const int kk = i / N, n = i - kk*N;
        const int kg = kc*32 + kk;
        lds[kk*N + n] = (kg < K) ? sb[(size_t)kg*N + n] : 0.f;
    }
    __syncthreads();
    const size_t base = ((size_t)r*KC + kc)*NF*512;
    for (int e = tid; e < NF*512; e += 256) {
        const int nf = e >> 9, rem = e & 511;
        const int l = rem >> 3, j = rem & 7;
        const int g = l >> 4, c = l & 15;
        const int kl = kmap2(g, j);
        const int n = nf*16 + c;
        const float v = (n < N) ? lds[kl*N + n] : 0.f;
        const half_t hi = (half_t)v;
        const half_t lo = (half_t)(v - (float)hi);
        dh[base + (size_t)nf*512 + rem] = hi;
        dl[base + (size_t)nf*512 + rem] = lo;
    }
}

// ---------------------------------------------------------------------------
// head_k: per-radical chain 200->140->84->42->4 fused, split-f16 MFMA.
// Weights LDS-staged per block; XCD-swizzled grid for L2 locality.
// ---------------------------------------------------------------------------
#define MFMA(a, b, c) __builtin_amdgcn_mfma_f32_16x16x32_f16(a, b, c, 0, 0, 0)

__global__ __launch_bounds__(256, 4) void head_k(
        const half_t* __restrict__ g0h, const half_t* __restrict__ g0l,
        const half_t* __restrict__ w1h, const half_t* __restrict__ w1l,
        const half_t* __restrict__ w2h, const half_t* __restrict__ w2l,
        const half_t* __restrict__ w3h, const half_t* __restrict__ w3l,
        const half_t* __restrict__ w4h, const half_t* __restrict__ w4l,
        const float* __restrict__ b1, const float* __restrict__ b2,
        const float* __restrict__ b3, const float* __restrict__ b4,
        float* __restrict__ out) {
    __shared__ half_t wb[18*512];
    __shared__ float bl[270];
    const int bid = blockIdx.x;
    const int cx  = bid & 7;
    const int kb  = bid >> 3;
    const int r   = ((kb >> 3) << 3) + cx;
    if (r >= NR) return;
    const int mt  = kb & 7;
    const int tid = threadIdx.x;
    if (tid < 140) bl[tid]       = b1[(size_t)r*140 + tid];
    if (tid < 84)  bl[140 + tid] = b2[(size_t)r*84  + tid];
    if (tid < 42)  bl[224 + tid] = b3[(size_t)r*42  + tid];
    if (tid < 4)   bl[266 + tid] = b4[(size_t)r*4   + tid];
    const int w = tid >> 6, l = tid & 63;
    const int g4 = ((l >> 4) & 3) * 4;
    const int mb0 = mt*8 + w*2;
    const size_t loff = (size_t)l * 8;

    // ===================== L1: K=200 (7 chunks), N=140 (9 frags) ==========
    f32x4 a1[2][9] = {};
    for (int kc = 0; kc < 7; ++kc) {
        const half_t* hs = w1h + ((size_t)r*7 + kc)*9*512;
        const half_t* ls = w1l + ((size_t)r*7 + kc)*9*512;
        #pragma unroll
        for (int p0 = 0; p0 < 3; ++p0) {
            const int p = w + p0*4;
            if (p < 9) {
                GLDS(hs + (size_t)p*512 + loff, wb + p*512);
                GLDS(ls + (size_t)p*512 + loff, wb + (9+p)*512);
            }
        }
        f16x8 bh[2], blo[2];
        #pragma unroll
        for (int mb = 0; mb < 2; ++mb) {
            const size_t bo = ((size_t)(mb0 + mb)*7 + kc)*512 + loff;
            bh[mb]  = *(const f16x8*)(g0h + bo);
            blo[mb] = *(const f16x8*)(g0l + bo);
        }
        __syncthreads();
        #pragma unroll
        for (int nf = 0; nf < 9; ++nf) {
            const f16x8 wh = *(const f16x8*)(wb + nf*512 + loff);
            const f16x8 wl = *(const f16x8*)(wb + (9+nf)*512 + loff);
            #pragma unroll
            for (int mb = 0; mb < 2; ++mb) {
                a1[mb][nf] = MFMA(wh, bh[mb],  a1[mb][nf]);
                a1[mb][nf] = MFMA(wh, blo[mb], a1[mb][nf]);
                a1[mb][nf] = MFMA(wl, bh[mb],  a1[mb][nf]);
            }
        }
        __syncthreads();
    }
    // ---- convert a1 -> L2 B-fragments (bias+relu+split), N1=140 ----
    f16x8 b2h[2][5], b2l[2][5];
    #pragma unroll
    for (int kc = 0; kc < 5; ++kc)
        #pragma unroll
        for (int h = 0; h < 2; ++h) {
            const int nf = kc*2 + h;
            #pragma unroll
            for (int mb = 0; mb < 2; ++mb)
                #pragma unroll
                for (int rr = 0; rr < 4; ++rr) {
                    float v = 0.f;
                    if (nf < 9) {
                        const int n = nf*16 + g4 + rr;
                        v = (n < 140) ? fmaxf(a1[mb][nf][rr] + bl[n], 0.f) : 0.f;
                    }
                    const half_t hi = (half_t)v;
                    const half_t lo = (half_t)(v - (float)hi);
                    b2h[mb][kc][h*4+rr] = hi;
                    b2l[mb][kc][h*4+rr] = lo;
                }
        }
    // ===================== L2: K=140 (5 chunks), N=84 (6 frags) ===========
    f32x4 a2[2][6] = {};
    for (int kc = 0; kc < 5; ++kc) {
        const half_t* hs = w2h + ((size_t)r*5 + kc)*6*512;
        const half_t* ls = w2l + ((size_t)r*5 + kc)*6*512;
        #pragma unroll
        for (int p0 = 0; p0 < 2; ++p0) {
            const int p = w + p0*4;
            if (p < 6) {
                GLDS(hs + (size_t)p*512 + loff, wb + p*512);
                GLDS(ls + (size_t)p*512 + loff, wb + (6+p)*512);
            }
        }
        __syncthreads();
        #pragma unroll
        for (int nf = 0; nf < 6; ++nf) {
            const f16x8 wh = *(const f16x8*)(wb + nf*512 + loff);
            const f16x8 wl = *(const f16x8*)(wb + (6+nf)*512 + loff);
            #pragma unroll
            for (int mb = 0; mb < 2; ++mb) {
                a2[mb][nf] = MFMA(wh, b2h[mb][kc], a2[mb][nf]);
                a2[mb][nf] = MFMA(wh, b2l[mb][kc], a2[mb][nf]);
                a2[mb][nf] = MFMA(wl, b2h[mb][kc], a2[mb][nf]);
            }
        }
        __syncthreads();
    }
    // ---- convert a2 -> L3 B-fragments, N2=84 ----
    f16x8 b3h[2][3], b3l[2][3];
    #pragma unroll
    for (int kc = 0; kc < 3; ++kc)
        #pragma unroll
        for (int h = 0; h < 2; ++h) {
            const int nf = kc*2 + h;
            #pragma unroll
            for (int mb = 0; mb < 2; ++mb)
                #pragma unroll
                for (int rr = 0; rr < 4; ++rr) {
                    float v = 0.f;
                    if (nf < 6) {
                        const int n = nf*16 + g4 + rr;
                        v = (n < 84) ? fmaxf(a2[mb][nf][rr] + bl[140 + n], 0.f) : 0.f;
                    }
                    const half_t hi = (half_t)v;
                    const half_t lo = (half_t)(v - (float)hi);
                    b3h[mb][kc][h*4+rr] = hi;
                    b3l[mb][kc][h*4+rr] = lo;
                }
        }
    // ===================== L3: K=84 (3 chunks), N=42 (3 frags) ============
    f32x4 a3[2][3] = {};
    for (int kc = 0; kc < 3; ++kc) {
        const half_t* hs = w3h + ((size_t)r*3 + kc)*3*512;
        const half_t* ls = w3l + ((size_t)r*3 + kc)*3*512;
        {
            const int p = w;
            if (p < 3) {
                GLDS(hs + (size_t)p*512 + loff, wb + p*512);
                GLDS(ls + (size_t)p*512 + loff, wb + (3+p)*512);
            }
        }
        __syncthreads();
        #pragma unroll
        for (int nf = 0; nf < 3; ++nf) {
            const f16x8 wh = *(const f16x8*)(wb + nf*512 + loff);
            const f16x8 wl = *(const f16x8*)(wb + (3+nf)*512 + loff);
            #pragma unroll
            for (int mb = 0; mb < 2; ++mb) {
                a3[mb][nf] = MFMA(wh, b3h[mb][kc], a3[mb][nf]);
                a3[mb][nf] = MFMA(wh, b3l[mb][kc], a3[mb][nf]);
                a3[mb][nf] = MFMA(wl, b3h[mb][kc], a3[mb][nf]);
            }
        }
        __syncthreads();
    }
    // ---- convert a3 -> L4 B-fragments, N3=42 ----
    f16x8 b4h[2][2], b4l[2][2];
    #pragma unroll
    for (int kc = 0; kc < 2; ++kc)
        #pragma unroll
        for (int h = 0; h < 2; ++h) {
            const int nf = kc*2 + h;
            #pragma unroll
            for (int mb = 0; mb < 2; ++mb)
                #pragma unroll
                for (int rr = 0; rr < 4; ++rr) {
                    float v = 0.f;
                    if (nf < 3) {
                        const int n = nf*16 + g4 + rr;
                        v = (n < 42) ? fmaxf(a3[mb][nf][rr] + bl[224 + n], 0.f) : 0.f;
                    }
                    const half_t hi = (half_t)v;
                    const half_t lo = (half_t)(v - (float)hi);
                    b4h[mb][kc][h*4+rr] = hi;
                    b4l[mb][kc][h*4+rr] = lo;
                }
        }
    // ===================== L4: K=42 (2 chunks), N=4 — direct global =======
    f32x4 a4[2] = {};
    #pragma unroll
    for (int kc = 0; kc < 2; ++kc) {
        const size_t wo = ((size_t)r*2 + kc)*512 + loff;
        const f16x8 wh = *(const f16x8*)(w4h + wo);
        const f16x8 wl = *(const f16x8*)(w4l + wo);
        #pragma unroll
        for (int mb = 0; mb < 2; ++mb) {
            a4[mb] = MFMA(wh, b4h[mb][kc], a4[mb]);
            a4[mb] = MFMA(wh, b4l[mb][kc], a4[mb]);
            a4[mb] = MFMA(wl, b4h[mb][kc], a4[mb]);
        }
    }
    if ((l >> 4) == 0) {
        #pragma unroll
        for (int mb = 0; mb < 2; ++mb) {
            const int b = (mb0 + mb)*16 + (l & 15);
            float4 o;
            o.x = a4[mb][0] + bl[266];
            o.y = a4[mb][1] + bl[267];
            o.z = a4[mb][2] + bl[268];
            o.w = a4[mb][3] + bl[269];
            *(float4*)(out + (size_t)b*400 + r*4) = o;
        }
    }
}

extern "C" void kernel_launch(void* const* d_in, const int* in_sizes, int n_in,
                              void* d_out, int out_size, void* d_ws, size_t ws_size,
                              hipStream_t stream) {
    const float* x    = (const float*)d_in[0];
    const float* c1w  = (const float*)d_in[1];
    const float* c1b  = (const float*)d_in[2];
    const float* c2w  = (const float*)d_in[3];
    const float* c2b  = (const float*)d_in[4];
    const float* c3w  = (const float*)d_in[5];
    const float* c3b  = (const float*)d_in[6];
    const float* fc1w = (const float*)d_in[7];
    const float* fc1b = (const float*)d_in[8];
    const float* fc2w = (const float*)d_in[9];
    const float* fc2b = (const float*)d_in[10];
    const float* h1w  = (const float*)d_in[11];
    const float* h1b  = (const float*)d_in[12];
    const float* h2w  = (const float*)d_in[13];
    const float* h2b  = (const float*)d_in[14];
    const float* h3w  = (const float*)d_in[15];
    const float* h3b  = (const float*)d_in[16];
    const float* h4w  = (const float*)d_in[17];
    const float* h4b  = (const float*)d_in[18];
    float* out = (float*)d_out;

    char* ws = (char*)d_ws;
    size_t o = 0;
    float* t1 = (float*)(ws + o); o += (size_t)NB*6*2401*4;
    float* t2 = (float*)(ws + o); o += (size_t)NB*4*484*4;
    float* t3 = (float*)(ws + o); o += (size_t)NB*200*4;
    float* f1 = (float*)(ws + o); o += (size_t)NB*400*4;
    half_t* g0h = (half_t*)(ws + o); o += (size_t)64*7*512*2;
    half_t* g0l = (half_t*)(ws + o); o += (size_t)64*7*512*2;
    half_t* w1h = (half_t*)(ws + o); o += (size_t)NR*7*9*512*2;
    half_t* w1l = (half_t*)(ws + o); o += (size_t)NR*7*9*512*2;
    half_t* w2h = (half_t*)(ws + o); o += (size_t)NR*5*6*512*2;
    half_t* w2l = (half_t*)(ws + o); o += (size_t)NR*5*6*512*2;
    half_t* w3h = (half_t*)(ws + o); o += (size_t)NR*3*3*512*2;
    half_t* w3l = (half_t*)(ws + o); o += (size_t)NR*3*3*512*2;
    half_t* w4h = (half_t*)(ws + o); o += (size_t)NR*2*1*512*2;
    half_t* w4l = (half_t*)(ws + o); o += (size_t)NR*2*1*512*2;

    hipMemsetAsync(g0h, 0, (size_t)64*7*512*2*2, stream);

    wsplit_k<<<dim3(17, NR), 256, 0, stream>>>(h1w, h2w, h3w, h4w,
        w1h, w1l, w2h, w2l, w3h, w3l, w4h, w4l);

    conv1_k<<<NB, 256, 0, stream>>>(x, c1w, c1b, t1);
    conv2_k<<<NB*4, 256, 0, stream>>>(t1, c2w, c2b, t2);
    conv3_k<<<NB, 256, 0, stream>>>(t2, c3w, c3b, t3);

    gemm_k<false><<<dim3(7, 8), 256, 0, stream>>>(
        t3, 200, fc1w, fc1b, f1, 400, NB, 400, 200, nullptr, nullptr);
    gemm_k<true><<<dim3(4, 8), 256, 0, stream>>>(
        f1, 400, fc2w, fc2b, nullptr, 0, NB, 200, 400, g0h, g0l);

    head_k<<<832, 256, 0, stream>>>(
        g0h, g0l, w1h, w1l, w2h, w2l, w3h, w3l, w4h, w4l,
        h1b, h2b, h3b, h4b, out);

    (void)in_sizes; (void)n_in; (void)out_size; (void)ws_size;
}